// Round 2
// baseline (556.792 us; speedup 1.0000x reference)
//
#include <hip/hip_runtime.h>
#include <hip/hip_bf16.h>
#include <math.h>

#define N_NODES 50000
#define N_EDGES 800000
#define F_DIM 128
#define H_DIM 64
#define IN_DIM 129   // F_DIM + 1 (binary feature)

// ---------------------------------------------------------------------------
// K1: xl = x @ Wl.T + bl ; xr = x @ Wr.T + br   (x = [x_float | x_binary])
// Block = 256 threads: 2 nodes per iteration, 128 output channels each
// (h<64 -> xl row, h>=64 -> xr row). Both W staged f32 in LDS, stride 129
// (odd) -> only 2-way bank aliasing (free on gfx950, m136).
// ---------------------------------------------------------------------------
__global__ __launch_bounds__(256) void proj_kernel(
    const float* __restrict__ xf, const float* __restrict__ xb,
    const float* __restrict__ Wl, const float* __restrict__ bl,
    const float* __restrict__ Wr, const float* __restrict__ br,
    float* __restrict__ xl, float* __restrict__ xr)
{
    __shared__ float wsh[128 * IN_DIM];   // 66 KB -> 2 blocks/CU
    int tid = threadIdx.x;
    for (int idx = tid; idx < 128 * IN_DIM; idx += 256) {
        int r = idx / IN_DIM;
        int k = idx - r * IN_DIM;
        wsh[idx] = (r < 64) ? Wl[r * IN_DIM + k] : Wr[(r - 64) * IN_DIM + k];
    }
    __syncthreads();

    int half = tid >> 7;        // which of the 2 nodes this thread works on
    int h    = tid & 127;       // output channel (0..63 xl, 64..127 xr)
    const float* w = &wsh[h * IN_DIM];

    for (int n = blockIdx.x * 2 + half; n < N_NODES; n += gridDim.x * 2) {
        const float* xrow = xf + (size_t)n * F_DIM;
        float acc = 0.f;
        #pragma unroll 8
        for (int k = 0; k < F_DIM; ++k) acc += xrow[k] * w[k];
        acc += xb[n] * w[F_DIM];
        if (h < 64) xl[n * H_DIM + h]        = acc + bl[h];
        else        xr[n * H_DIM + (h - 64)] = acc + br[h - 64];
    }
}

// ---------------------------------------------------------------------------
// K2: one wave per edge (incl. self loops at indices >= E).
//   e  = att . leakyrelu(xl[src] + xr[dst])   (no max-subtraction: |e| < ~8,
//                                              exp(e) <= ~300, no overflow)
//   denom[dst]    += exp(e)            (lane 0 atomic)
//   accum[dst][l] += exp(e)*xl[src][l] (64 consecutive-address f32 atomics)
// ---------------------------------------------------------------------------
__global__ __launch_bounds__(256) void edge_kernel(
    const int* __restrict__ esrc, const int* __restrict__ edst,
    const float* __restrict__ xl, const float* __restrict__ xr,
    const float* __restrict__ att,
    float* __restrict__ accum, float* __restrict__ denom)
{
    int gid  = blockIdx.x * 256 + threadIdx.x;
    int wid  = gid >> 6;                 // edge index (wave-uniform)
    int lane = threadIdx.x & 63;
    const int ET = N_EDGES + N_NODES;
    if (wid >= ET) return;

    int src, dst;
    if (wid < N_EDGES) { src = esrc[wid]; dst = edst[wid]; }
    else               { src = wid - N_EDGES; dst = src; }

    float xlv = xl[(size_t)src * H_DIM + lane];
    float xrv = xr[(size_t)dst * H_DIM + lane];
    float m = xlv + xrv;
    m = (m > 0.f) ? m : 0.2f * m;
    float p = m * att[lane];

    #pragma unroll
    for (int off = 32; off >= 1; off >>= 1) p += __shfl_xor(p, off);

    float ex = __expf(p);
    if (lane == 0) atomicAdd(&denom[dst], ex);
    atomicAdd(&accum[(size_t)dst * H_DIM + lane], ex * xlv);
}

// ---------------------------------------------------------------------------
// K3: h = elu(accum/denom + gat_bias), written in place over accum.
// ---------------------------------------------------------------------------
__global__ __launch_bounds__(256) void node_kernel(
    float* __restrict__ accum, const float* __restrict__ denom,
    const float* __restrict__ gat_bias)
{
    int i = blockIdx.x * 256 + threadIdx.x;
    if (i >= N_NODES * H_DIM) return;
    int n = i >> 6;
    int l = i & 63;
    float v = accum[i] / denom[n] + gat_bias[l];
    v = (v > 0.f) ? v : expm1f(v);
    accum[i] = v;
}

// ---------------------------------------------------------------------------
// K4: logits = h @ Wo.T + bo (f32 out), + softplus(dispersion) tail.
// Wo staged f32 in LDS with stride 65 (odd) to avoid wide bank conflicts.
// ---------------------------------------------------------------------------
__global__ __launch_bounds__(256) void out_kernel(
    const float* __restrict__ hbuf, const float* __restrict__ Wo,
    const float* __restrict__ bo, const float* __restrict__ disp,
    float* __restrict__ out)
{
    __shared__ float wsh[128 * 65];   // 33 KB
    int tid = threadIdx.x;
    for (int idx = tid; idx < 128 * 64; idx += 256) {
        int r = idx >> 6, k = idx & 63;
        wsh[r * 65 + k] = Wo[idx];
    }
    __syncthreads();

    if (blockIdx.x == 0 && tid < F_DIM) {
        float d  = disp[tid];
        float sp = (d > 20.f) ? d : log1pf(__expf(d));
        out[(size_t)N_NODES * F_DIM + tid] = sp;
    }

    int half = tid >> 7;
    int h    = tid & 127;
    const float* w = &wsh[h * 65];

    for (int n = blockIdx.x * 2 + half; n < N_NODES; n += gridDim.x * 2) {
        const float* hrow = hbuf + (size_t)n * H_DIM;
        float acc = 0.f;
        #pragma unroll
        for (int k = 0; k < H_DIM; ++k) acc += hrow[k] * w[k];
        out[(size_t)n * F_DIM + h] = acc + bo[h];
    }
}

// ---------------------------------------------------------------------------
extern "C" void kernel_launch(void* const* d_in, const int* in_sizes, int n_in,
                              void* d_out, int out_size, void* d_ws, size_t ws_size,
                              hipStream_t stream)
{
    const float* xf  = (const float*)d_in[0];
    const float* xb  = (const float*)d_in[1];
    const int*   ei  = (const int*)d_in[2];    // [2, E] int32, row-major
    const float* Wl  = (const float*)d_in[3];
    const float* bl  = (const float*)d_in[4];
    const float* Wr  = (const float*)d_in[5];
    const float* br  = (const float*)d_in[6];
    const float* att = (const float*)d_in[7];
    const float* gb  = (const float*)d_in[8];
    const float* Wo  = (const float*)d_in[9];
    const float* bo  = (const float*)d_in[10];
    const float* dp  = (const float*)d_in[11];
    float* out = (float*)d_out;

    // ws layout (f32): xl[N*64] | xr[N*64] | accum[N*64] | denom[N]
    char* ws = (char*)d_ws;
    const size_t SZ = (size_t)N_NODES * H_DIM * sizeof(float);   // 12.8 MB
    float* xl    = (float*)(ws);
    float* xr    = (float*)(ws + SZ);
    float* accum = (float*)(ws + 2 * SZ);
    float* denom = (float*)(ws + 3 * SZ);

    // zero the atomic accumulators (accum + denom are contiguous)
    hipMemsetAsync(accum, 0, SZ + (size_t)N_NODES * sizeof(float), stream);

    proj_kernel<<<2048, 256, 0, stream>>>(xf, xb, Wl, bl, Wr, br, xl, xr);

    const int ET   = N_EDGES + N_NODES;            // 850000 edges
    const int nblk = (ET * 64 + 255) / 256;        // one wave per edge
    edge_kernel<<<nblk, 256, 0, stream>>>(ei, ei + N_EDGES, xl, xr, att,
                                          accum, denom);

    node_kernel<<<(N_NODES * H_DIM + 255) / 256, 256, 0, stream>>>(accum, denom, gb);

    out_kernel<<<2048, 256, 0, stream>>>(accum, Wo, bo, dp, out);
}

// Round 3
// 433.899 us; speedup vs baseline: 1.2832x; 1.2832x over previous
//
#include <hip/hip_runtime.h>
#include <hip/hip_bf16.h>
#include <math.h>

#define N_NODES 50000
#define N_EDGES 800000
#define F_DIM 128
#define H_DIM 64
#define IN_DIM 129   // F_DIM + 1 (binary feature)
#define WS 132       // padded f32 stride for proj W rows (16B-aligned, %32==4)
#define OWS 68       // padded f32 stride for out W rows
#define PT 16        // nodes per tile (50000 = 3125 * 16 exactly)

typedef __hip_bfloat16 bf16;
static __device__ __forceinline__ float b2f(bf16 x) { return __bfloat162float(x); }

// ---------------------------------------------------------------------------
// K1: xl = x @ Wl.T + bl ; xr = x @ Wr.T + br  (x = [x_float | x_binary])
// LDS-tiled: W (both, 128 rows x 129) staged once per block at stride 132;
// X tile of 16 nodes staged via coalesced float4. Each wave-pair handles 8
// nodes with register blocking: one W float4 read is reused for 8 nodes ->
// W LDS traffic /8. Outputs stored bf16 (halves edge-phase gather bytes).
// ---------------------------------------------------------------------------
__global__ __launch_bounds__(256) void proj_kernel(
    const float* __restrict__ xf, const float* __restrict__ xb,
    const float* __restrict__ Wl, const float* __restrict__ bl,
    const float* __restrict__ Wr, const float* __restrict__ br,
    bf16* __restrict__ xl, bf16* __restrict__ xr)
{
    __shared__ float wsh[128 * WS];   // 67.6 KB
    __shared__ float xsh[PT * WS];    // 8.4 KB  -> 76 KB total, 2 blocks/CU
    int tid = threadIdx.x;

    for (int idx = tid; idx < 128 * IN_DIM; idx += 256) {
        int r = idx / IN_DIM, k = idx - r * IN_DIM;
        wsh[r * WS + k] = (r < 64) ? Wl[r * IN_DIM + k]
                                   : Wr[(r - 64) * IN_DIM + k];
    }

    int node0 = blockIdx.x * PT;
    {
        const float4* xf4 = (const float4*)(xf + (size_t)node0 * F_DIM);
        for (int i = tid; i < PT * 32; i += 256) {   // 32 float4 per row
            int r = i >> 5, c = i & 31;
            float4 v = xf4[(size_t)r * 32 + c];
            float* d = &xsh[r * WS + c * 4];
            d[0] = v.x; d[1] = v.y; d[2] = v.z; d[3] = v.w;
        }
        if (tid < PT) xsh[tid * WS + 128] = xb[node0 + tid];
    }
    __syncthreads();

    int half = tid >> 7;          // waves 0-1 -> nodes r0..r0+7 with r0=0; waves 2-3 -> 8..15
    int h    = tid & 127;         // output channel (0..63 xl, 64..127 xr)
    const float4* wv = (const float4*)&wsh[h * WS];
    float wlast = wsh[h * WS + 128];
    int r0 = half * 8;

    float acc[8];
    #pragma unroll
    for (int i = 0; i < 8; ++i) acc[i] = xsh[(r0 + i) * WS + 128] * wlast;

    #pragma unroll 8
    for (int k4 = 0; k4 < 32; ++k4) {
        float4 w = wv[k4];
        #pragma unroll
        for (int i = 0; i < 8; ++i) {
            const float* xp = &xsh[(r0 + i) * WS + k4 * 4];
            acc[i] += xp[0] * w.x + xp[1] * w.y + xp[2] * w.z + xp[3] * w.w;
        }
    }

    int hh = h & 63;
    bf16* dstp = (h < 64) ? xl : xr;
    float bv = (h < 64) ? bl[hh] : br[hh];
    #pragma unroll
    for (int i = 0; i < 8; ++i) {
        int n = node0 + r0 + i;
        dstp[(size_t)n * H_DIM + hh] = __float2bfloat16(acc[i] + bv);
    }
}

// ---------------------------------------------------------------------------
// K2: one wave per edge (incl. self loops at indices >= E). bf16 gathers.
//   e  = att . leakyrelu(xl[src] + xr[dst])   (no max-subtraction: |e| < ~8)
//   denom[dst]    += exp(e)            (lane 0 atomic)
//   accum[dst][l] += exp(e)*xl[src][l] (64 consecutive-address f32 atomics)
// ---------------------------------------------------------------------------
__global__ __launch_bounds__(256) void edge_kernel(
    const int* __restrict__ esrc, const int* __restrict__ edst,
    const bf16* __restrict__ xl, const bf16* __restrict__ xr,
    const float* __restrict__ att,
    float* __restrict__ accum, float* __restrict__ denom)
{
    int gid  = blockIdx.x * 256 + threadIdx.x;
    int wid  = gid >> 6;                 // edge index (wave-uniform)
    int lane = threadIdx.x & 63;
    const int ET = N_EDGES + N_NODES;
    if (wid >= ET) return;

    int src, dst;
    if (wid < N_EDGES) { src = esrc[wid]; dst = edst[wid]; }
    else               { src = wid - N_EDGES; dst = src; }

    float xlv = b2f(xl[(size_t)src * H_DIM + lane]);
    float xrv = b2f(xr[(size_t)dst * H_DIM + lane]);
    float m = xlv + xrv;
    m = (m > 0.f) ? m : 0.2f * m;
    float p = m * att[lane];

    #pragma unroll
    for (int off = 32; off >= 1; off >>= 1) p += __shfl_xor(p, off);

    float ex = __expf(p);
    if (lane == 0) atomicAdd(&denom[dst], ex);
    atomicAdd(&accum[(size_t)dst * H_DIM + lane], ex * xlv);
}

// ---------------------------------------------------------------------------
// K3 (fused node epilogue + output GEMM):
//   h = elu(accum/denom + gat_bias)  applied while staging the h tile in LDS,
//   logits = h @ Wo.T + bo, plus the softplus(dispersion) tail on block 0.
// Same register-blocked LDS-GEMM structure as K1 (K=64 here).
// ---------------------------------------------------------------------------
__global__ __launch_bounds__(256) void out_kernel(
    const float* __restrict__ accum, const float* __restrict__ denom,
    const float* __restrict__ gb,
    const float* __restrict__ Wo, const float* __restrict__ bo,
    const float* __restrict__ disp, float* __restrict__ out)
{
    __shared__ float wsh[128 * OWS];   // 34.8 KB
    __shared__ float hsh[PT * OWS];    // 4.35 KB
    int tid = threadIdx.x;

    for (int idx = tid; idx < 128 * 64; idx += 256) {
        int r = idx >> 6, k = idx & 63;
        wsh[r * OWS + k] = Wo[idx];
    }

    int node0 = blockIdx.x * PT;
    {
        const float4* a4 = (const float4*)(accum + (size_t)node0 * H_DIM);
        const float4* g4 = (const float4*)gb;
        // PT*16 float4 = exactly one per thread
        int r = tid >> 4, c = tid & 15;
        float4 v = a4[(size_t)r * 16 + c];
        float inv = 1.0f / denom[node0 + r];
        float4 g = g4[c];
        float o0 = v.x * inv + g.x;  o0 = (o0 > 0.f) ? o0 : expm1f(o0);
        float o1 = v.y * inv + g.y;  o1 = (o1 > 0.f) ? o1 : expm1f(o1);
        float o2 = v.z * inv + g.z;  o2 = (o2 > 0.f) ? o2 : expm1f(o2);
        float o3 = v.w * inv + g.w;  o3 = (o3 > 0.f) ? o3 : expm1f(o3);
        float* d = &hsh[r * OWS + c * 4];
        d[0] = o0; d[1] = o1; d[2] = o2; d[3] = o3;
    }
    __syncthreads();

    if (blockIdx.x == 0 && tid < F_DIM) {
        float d  = disp[tid];
        out[(size_t)N_NODES * F_DIM + tid] = (d > 20.f) ? d : log1pf(__expf(d));
    }

    int half = tid >> 7;
    int h    = tid & 127;
    const float4* wv = (const float4*)&wsh[h * OWS];
    int r0 = half * 8;

    float acc[8] = {0.f, 0.f, 0.f, 0.f, 0.f, 0.f, 0.f, 0.f};
    #pragma unroll
    for (int k4 = 0; k4 < 16; ++k4) {
        float4 w = wv[k4];
        #pragma unroll
        for (int i = 0; i < 8; ++i) {
            const float* xp = &hsh[(r0 + i) * OWS + k4 * 4];
            acc[i] += xp[0] * w.x + xp[1] * w.y + xp[2] * w.z + xp[3] * w.w;
        }
    }

    float bv = bo[h];
    #pragma unroll
    for (int i = 0; i < 8; ++i) {
        int n = node0 + r0 + i;
        out[(size_t)n * F_DIM + h] = acc[i] + bv;
    }
}

// ---------------------------------------------------------------------------
extern "C" void kernel_launch(void* const* d_in, const int* in_sizes, int n_in,
                              void* d_out, int out_size, void* d_ws, size_t ws_size,
                              hipStream_t stream)
{
    const float* xf  = (const float*)d_in[0];
    const float* xb  = (const float*)d_in[1];
    const int*   ei  = (const int*)d_in[2];    // [2, E] int32, row-major
    const float* Wl  = (const float*)d_in[3];
    const float* bl  = (const float*)d_in[4];
    const float* Wr  = (const float*)d_in[5];
    const float* br  = (const float*)d_in[6];
    const float* att = (const float*)d_in[7];
    const float* gb  = (const float*)d_in[8];
    const float* Wo  = (const float*)d_in[9];
    const float* bo  = (const float*)d_in[10];
    const float* dp  = (const float*)d_in[11];
    float* out = (float*)d_out;

    // ws layout: xl bf16[N*64] | xr bf16[N*64] | accum f32[N*64] | denom f32[N]
    char* ws = (char*)d_ws;
    const size_t SZB = (size_t)N_NODES * H_DIM * sizeof(bf16);   // 6.4 MB
    const size_t SZF = (size_t)N_NODES * H_DIM * sizeof(float);  // 12.8 MB
    bf16*  xl    = (bf16*)(ws);
    bf16*  xr    = (bf16*)(ws + SZB);
    float* accum = (float*)(ws + 2 * SZB);
    float* denom = (float*)(ws + 2 * SZB + SZF);

    // zero the atomic accumulators (accum + denom are contiguous)
    hipMemsetAsync(accum, 0, SZF + (size_t)N_NODES * sizeof(float), stream);

    proj_kernel<<<N_NODES / PT, 256, 0, stream>>>(xf, xb, Wl, bl, Wr, br, xl, xr);

    const int ET   = N_EDGES + N_NODES;            // 850000 edges
    const int nblk = (ET * 64 + 255) / 256;        // one wave per edge
    edge_kernel<<<nblk, 256, 0, stream>>>(ei, ei + N_EDGES, xl, xr, att,
                                          accum, denom);

    out_kernel<<<N_NODES / PT, 256, 0, stream>>>(accum, denom, gb, Wo, bo, dp, out);
}

// Round 4
// 389.308 us; speedup vs baseline: 1.4302x; 1.1145x over previous
//
#include <hip/hip_runtime.h>
#include <hip/hip_bf16.h>
#include <math.h>

#define N_NODES 50000
#define N_EDGES 800000
#define F_DIM 128
#define H_DIM 64
#define IN_DIM 129   // F_DIM + 1 (binary feature)
#define WS 132       // padded f32 stride for proj W rows
#define OWS 68       // padded f32 stride for out W rows
#define PT 16        // nodes per GEMM tile (50000 = 3125 * 16)
#define NPAD 50176   // 196 * 256 (scan-padded node count)

typedef __hip_bfloat16 bf16;
static __device__ __forceinline__ float b2f(bf16 x) { return __bfloat162float(x); }

// ---------------------------------------------------------------------------
// K1: xl = x @ Wl.T + bl ; xr = x @ Wr.T + br  (unchanged from R3)
// ---------------------------------------------------------------------------
__global__ __launch_bounds__(256) void proj_kernel(
    const float* __restrict__ xf, const float* __restrict__ xb,
    const float* __restrict__ Wl, const float* __restrict__ bl,
    const float* __restrict__ Wr, const float* __restrict__ br,
    bf16* __restrict__ xl, bf16* __restrict__ xr)
{
    __shared__ float wsh[128 * WS];   // 67.6 KB
    __shared__ float xsh[PT * WS];    // 8.4 KB
    int tid = threadIdx.x;

    for (int idx = tid; idx < 128 * IN_DIM; idx += 256) {
        int r = idx / IN_DIM, k = idx - r * IN_DIM;
        wsh[r * WS + k] = (r < 64) ? Wl[r * IN_DIM + k]
                                   : Wr[(r - 64) * IN_DIM + k];
    }

    int node0 = blockIdx.x * PT;
    {
        const float4* xf4 = (const float4*)(xf + (size_t)node0 * F_DIM);
        for (int i = tid; i < PT * 32; i += 256) {
            int r = i >> 5, c = i & 31;
            float4 v = xf4[(size_t)r * 32 + c];
            float* d = &xsh[r * WS + c * 4];
            d[0] = v.x; d[1] = v.y; d[2] = v.z; d[3] = v.w;
        }
        if (tid < PT) xsh[tid * WS + 128] = xb[node0 + tid];
    }
    __syncthreads();

    int half = tid >> 7;
    int h    = tid & 127;
    const float4* wv = (const float4*)&wsh[h * WS];
    float wlast = wsh[h * WS + 128];
    int r0 = half * 8;

    float acc[8];
    #pragma unroll
    for (int i = 0; i < 8; ++i) acc[i] = xsh[(r0 + i) * WS + 128] * wlast;

    #pragma unroll 8
    for (int k4 = 0; k4 < 32; ++k4) {
        float4 w = wv[k4];
        #pragma unroll
        for (int i = 0; i < 8; ++i) {
            const float* xp = &xsh[(r0 + i) * WS + k4 * 4];
            acc[i] += xp[0] * w.x + xp[1] * w.y + xp[2] * w.z + xp[3] * w.w;
        }
    }

    int hh = h & 63;
    bf16* dstp = (h < 64) ? xl : xr;
    float bv = (h < 64) ? bl[hh] : br[hh];
    #pragma unroll
    for (int i = 0; i < 8; ++i) {
        int n = node0 + r0 + i;
        dstp[(size_t)n * H_DIM + hh] = __float2bfloat16(acc[i] + bv);
    }
}

// ---------------------------------------------------------------------------
// CSR build: count -> 2-level exclusive scan -> scatter src ids by dst.
// ---------------------------------------------------------------------------
__global__ __launch_bounds__(256) void count_kernel(
    const int* __restrict__ edst, int* __restrict__ cnt)
{
    int e = blockIdx.x * 256 + threadIdx.x;
    if (e < N_EDGES) atomicAdd(&cnt[edst[e]], 1);
}

// block-local exclusive scan of 256 counts; emit block total
__global__ __launch_bounds__(256) void scan_a_kernel(
    const int* __restrict__ cnt, int* __restrict__ offs, int* __restrict__ bsum)
{
    __shared__ int s[256];
    int tid = threadIdx.x;
    int i = blockIdx.x * 256 + tid;
    int v = (i < N_NODES) ? cnt[i] : 0;
    s[tid] = v;
    __syncthreads();
    #pragma unroll
    for (int d = 1; d < 256; d <<= 1) {
        int t = (tid >= d) ? s[tid - d] : 0;
        __syncthreads();
        s[tid] += t;
        __syncthreads();
    }
    offs[i] = s[tid] - v;                 // exclusive (block-local)
    if (tid == 255) bsum[blockIdx.x] = s[255];
}

// single-block exclusive scan of the 196 block sums
__global__ __launch_bounds__(256) void scan_b_kernel(int* __restrict__ bsum)
{
    __shared__ int s[256];
    int tid = threadIdx.x;
    int v = (tid < 196) ? bsum[tid] : 0;
    s[tid] = v;
    __syncthreads();
    #pragma unroll
    for (int d = 1; d < 256; d <<= 1) {
        int t = (tid >= d) ? s[tid - d] : 0;
        __syncthreads();
        s[tid] += t;
        __syncthreads();
    }
    if (tid < 196) bsum[tid] = s[tid] - v;   // exclusive
}

__global__ __launch_bounds__(256) void scan_c_kernel(
    int* __restrict__ offs, const int* __restrict__ bsum)
{
    int i = blockIdx.x * 256 + threadIdx.x;
    offs[i] += bsum[blockIdx.x];
}

__global__ __launch_bounds__(256) void fill_kernel(
    const int* __restrict__ esrc, const int* __restrict__ edst,
    const int* __restrict__ offs, int* __restrict__ cur,
    int* __restrict__ csr_src)
{
    int e = blockIdx.x * 256 + threadIdx.x;
    if (e >= N_EDGES) return;
    int dst = edst[e];
    int pos = offs[dst] + atomicAdd(&cur[dst], 1);
    csr_src[pos] = esrc[e];
}

// ---------------------------------------------------------------------------
// K2: aggregation, one wave per dst node, NO atomics.
//   self-loop handled implicitly (not in CSR).
//   denom/acc in registers; h = elu(acc/denom + gat_bias) written once.
//   csr_src load pipelined one edge ahead of the xl gather.
// ---------------------------------------------------------------------------
__global__ __launch_bounds__(256) void agg_kernel(
    const int* __restrict__ csr_src, const int* __restrict__ offs,
    const bf16* __restrict__ xl, const bf16* __restrict__ xr,
    const float* __restrict__ att, const float* __restrict__ gb,
    float* __restrict__ h)
{
    int wid  = (blockIdx.x * 256 + threadIdx.x) >> 6;   // dst node
    int lane = threadIdx.x & 63;
    if (wid >= N_NODES) return;
    int dst = wid;

    float attv = att[lane];
    float xrv  = b2f(xr[(size_t)dst * H_DIM + lane]);

    // self loop
    float xls = b2f(xl[(size_t)dst * H_DIM + lane]);
    float m = xls + xrv;
    m = (m > 0.f) ? m : 0.2f * m;
    float p = m * attv;
    #pragma unroll
    for (int off = 32; off >= 1; off >>= 1) p += __shfl_xor(p, off);
    float ex  = __expf(p);
    float den = ex;
    float acc = ex * xls;

    int beg = offs[dst], end = offs[dst + 1];
    int s0 = (beg < end) ? csr_src[beg] : 0;
    for (int i = beg; i < end; ++i) {
        int s1 = (i + 1 < end) ? csr_src[i + 1] : 0;   // prefetch next src
        float xv = b2f(xl[(size_t)s0 * H_DIM + lane]);
        float mm = xv + xrv;
        mm = (mm > 0.f) ? mm : 0.2f * mm;
        float pp = mm * attv;
        #pragma unroll
        for (int off = 32; off >= 1; off >>= 1) pp += __shfl_xor(pp, off);
        float ee = __expf(pp);
        den += ee;
        acc += ee * xv;
        s0 = s1;
    }

    float v = acc / den + gb[lane];
    h[(size_t)dst * H_DIM + lane] = (v > 0.f) ? v : expm1f(v);
}

// ---------------------------------------------------------------------------
// K3: logits = h @ Wo.T + bo (+ softplus(dispersion) tail on block 0)
// ---------------------------------------------------------------------------
__global__ __launch_bounds__(256) void out_kernel(
    const float* __restrict__ hbuf,
    const float* __restrict__ Wo, const float* __restrict__ bo,
    const float* __restrict__ disp, float* __restrict__ out)
{
    __shared__ float wsh[128 * OWS];   // 34.8 KB
    __shared__ float hsh[PT * OWS];    // 4.35 KB
    int tid = threadIdx.x;

    for (int idx = tid; idx < 128 * 64; idx += 256) {
        int r = idx >> 6, k = idx & 63;
        wsh[r * OWS + k] = Wo[idx];
    }

    int node0 = blockIdx.x * PT;
    {
        const float4* h4 = (const float4*)(hbuf + (size_t)node0 * H_DIM);
        int r = tid >> 4, c = tid & 15;          // PT*16 float4 = 1/thread
        float4 v = h4[(size_t)r * 16 + c];
        float* d = &hsh[r * OWS + c * 4];
        d[0] = v.x; d[1] = v.y; d[2] = v.z; d[3] = v.w;
    }
    __syncthreads();

    if (blockIdx.x == 0 && tid < F_DIM) {
        float d  = disp[tid];
        out[(size_t)N_NODES * F_DIM + tid] = (d > 20.f) ? d : log1pf(__expf(d));
    }

    int half = tid >> 7;
    int h    = tid & 127;
    const float4* wv = (const float4*)&wsh[h * OWS];
    int r0 = half * 8;

    float acc[8] = {0.f, 0.f, 0.f, 0.f, 0.f, 0.f, 0.f, 0.f};
    #pragma unroll
    for (int k4 = 0; k4 < 16; ++k4) {
        float4 w = wv[k4];
        #pragma unroll
        for (int i = 0; i < 8; ++i) {
            const float* xp = &hsh[(r0 + i) * OWS + k4 * 4];
            acc[i] += xp[0] * w.x + xp[1] * w.y + xp[2] * w.z + xp[3] * w.w;
        }
    }

    float bv = bo[h];
    #pragma unroll
    for (int i = 0; i < 8; ++i) {
        int n = node0 + r0 + i;
        out[(size_t)n * F_DIM + h] = acc[i] + bv;
    }
}

// ---------------------------------------------------------------------------
extern "C" void kernel_launch(void* const* d_in, const int* in_sizes, int n_in,
                              void* d_out, int out_size, void* d_ws, size_t ws_size,
                              hipStream_t stream)
{
    const float* xf  = (const float*)d_in[0];
    const float* xb  = (const float*)d_in[1];
    const int*   ei  = (const int*)d_in[2];    // [2, E] int32, row-major
    const float* Wl  = (const float*)d_in[3];
    const float* bl  = (const float*)d_in[4];
    const float* Wr  = (const float*)d_in[5];
    const float* br  = (const float*)d_in[6];
    const float* att = (const float*)d_in[7];
    const float* gb  = (const float*)d_in[8];
    const float* Wo  = (const float*)d_in[9];
    const float* bo  = (const float*)d_in[10];
    const float* dp  = (const float*)d_in[11];
    float* out = (float*)d_out;
    const int* esrc = ei;
    const int* edst = ei + N_EDGES;

    // ws layout:
    //  xl bf16[N*64] | xr bf16[N*64] | h f32[N*64] | csr_src int[E] |
    //  cnt int[NPAD] | cur int[NPAD] | offs int[NPAD] | bsum int[256]
    char* ws = (char*)d_ws;
    const size_t SZB = (size_t)N_NODES * H_DIM * sizeof(bf16);   // 6.4 MB
    const size_t SZF = (size_t)N_NODES * H_DIM * sizeof(float);  // 12.8 MB
    bf16*  xl      = (bf16*)(ws);
    bf16*  xr      = (bf16*)(ws + SZB);
    float* h       = (float*)(ws + 2 * SZB);
    int*   csr_src = (int*)(ws + 2 * SZB + SZF);
    int*   cnt     = (int*)(ws + 2 * SZB + SZF + (size_t)N_EDGES * 4);
    int*   cur     = cnt + NPAD;
    int*   offs    = cur + NPAD;
    int*   bsum    = offs + NPAD;

    // zero cnt + cur (contiguous, 400 KB) — only counters need zeroing now
    hipMemsetAsync(cnt, 0, 2 * NPAD * sizeof(int), stream);

    proj_kernel<<<N_NODES / PT, 256, 0, stream>>>(xf, xb, Wl, bl, Wr, br, xl, xr);

    count_kernel<<<N_EDGES / 256, 256, 0, stream>>>(edst, cnt);
    scan_a_kernel<<<NPAD / 256, 256, 0, stream>>>(cnt, offs, bsum);
    scan_b_kernel<<<1, 256, 0, stream>>>(bsum);
    scan_c_kernel<<<NPAD / 256, 256, 0, stream>>>(offs, bsum);
    fill_kernel<<<N_EDGES / 256, 256, 0, stream>>>(esrc, edst, offs, cur, csr_src);

    agg_kernel<<<(N_NODES * 64) / 256, 256, 0, stream>>>(csr_src, offs, xl, xr,
                                                         att, gb, h);

    out_kernel<<<N_NODES / PT, 256, 0, stream>>>(h, Wo, bo, dp, out);
}

// Round 5
// 293.038 us; speedup vs baseline: 1.9001x; 1.3285x over previous
//
#include <hip/hip_runtime.h>
#include <hip/hip_bf16.h>
#include <math.h>

#define N_NODES 50000
#define N_EDGES 800000
#define F_DIM 128
#define H_DIM 64
#define IN_DIM 129   // F_DIM + 1 (binary feature)
#define NPAD 50176   // 196 * 256 (scan-padded node count)
#define WPS 136      // bf16 row stride, proj W  (136*2 = 272 B = 17*16, 16B-aligned rows)
#define WOS 72       // bf16 row stride, out W   (72*2 = 144 B = 9*16)

typedef __hip_bfloat16 bf16;
typedef __attribute__((ext_vector_type(8))) short bf16x8;   // MFMA A/B frag (4 VGPR)
typedef __attribute__((ext_vector_type(4))) float f32x4;    // MFMA C/D frag

static __device__ __forceinline__ float b2f(bf16 x) { return __bfloat162float(x); }
static __device__ __forceinline__ short f2bs(float f) {
    union { bf16 b; short s; } u; u.b = __float2bfloat16(f); return u.s;
}

// ---------------------------------------------------------------------------
// P0: split W matrices into bf16 hi/lo (hi+lo ~ f32 exact, err ~2^-17),
// stack [Wl;Wr] -> 128 rows x 129, col 128 kept f32 (wcol), bias stacked.
// ---------------------------------------------------------------------------
__global__ __launch_bounds__(256) void prep_kernel(
    const float* __restrict__ Wl, const float* __restrict__ bl,
    const float* __restrict__ Wr, const float* __restrict__ br,
    const float* __restrict__ Wo,
    bf16* __restrict__ wphi, bf16* __restrict__ wplo,
    float* __restrict__ wcol, float* __restrict__ biasP,
    bf16* __restrict__ wohi, bf16* __restrict__ wolo)
{
    int tid  = blockIdx.x * 256 + threadIdx.x;
    int nthr = gridDim.x * 256;
    for (int idx = tid; idx < 128 * IN_DIM; idx += nthr) {
        int r = idx / IN_DIM, k = idx - r * IN_DIM;
        float v = (r < 64) ? Wl[r * IN_DIM + k] : Wr[(r - 64) * IN_DIM + k];
        if (k == 128) {
            wcol[r] = v;
        } else {
            bf16 hi = __float2bfloat16(v);
            wphi[r * WPS + k] = hi;
            wplo[r * WPS + k] = __float2bfloat16(v - b2f(hi));
        }
    }
    for (int idx = tid; idx < 128 * 64; idx += nthr) {
        int r = idx >> 6, k = idx & 63;
        float v = Wo[idx];
        bf16 hi = __float2bfloat16(v);
        wohi[r * WOS + k] = hi;
        wolo[r * WOS + k] = __float2bfloat16(v - b2f(hi));
    }
    if (tid < 128) biasP[tid] = (tid < 64) ? bl[tid] : br[tid - 64];
}

// ---------------------------------------------------------------------------
// K1 (MFMA): [xl|xr] = x @ [Wl;Wr]^T + bias.  Block = 64 nodes x 128 ch.
// Wave w owns channels [w*32, w*32+32) (2 N-tiles); B-frags (W hi/lo) held in
// registers for the whole kernel — NO LDS. A-frags load straight from global
// (k-contiguous 8-f32 -> cvt bf16). K=128 via 4 MFMA ksteps; binary column
// (k=128) folded into the epilogue in f32.
// ---------------------------------------------------------------------------
__global__ __launch_bounds__(256) void proj_mfma(
    const float* __restrict__ xf, const float* __restrict__ xb,
    const bf16* __restrict__ wphi, const bf16* __restrict__ wplo,
    const float* __restrict__ wcol, const float* __restrict__ biasP,
    bf16* __restrict__ xl, bf16* __restrict__ xr)
{
    int wave = threadIdx.x >> 6;
    int lane = threadIdx.x & 63;
    int n = lane & 15, q = lane >> 4;
    int node0 = blockIdx.x * 64;

    bf16x8 bhi[2][4], blo[2][4];
    float biasv[2], w128[2];
    #pragma unroll
    for (int nt = 0; nt < 2; ++nt) {
        int ch = wave * 32 + nt * 16 + n;
        #pragma unroll
        for (int ks = 0; ks < 4; ++ks) {
            bhi[nt][ks] = *(const bf16x8*)(wphi + ch * WPS + ks * 32 + q * 8);
            blo[nt][ks] = *(const bf16x8*)(wplo + ch * WPS + ks * 32 + q * 8);
        }
        biasv[nt] = biasP[ch];
        w128[nt]  = wcol[ch];
    }

    #pragma unroll
    for (int mt = 0; mt < 4; ++mt) {
        int nb = node0 + mt * 16;
        if (nb >= N_NODES) break;
        const float* xrow = xf + (size_t)(nb + n) * F_DIM;
        bf16x8 a[4];
        #pragma unroll
        for (int ks = 0; ks < 4; ++ks) {
            float4 u = *(const float4*)(xrow + ks * 32 + q * 8);
            float4 v = *(const float4*)(xrow + ks * 32 + q * 8 + 4);
            bf16x8 t;
            t[0] = f2bs(u.x); t[1] = f2bs(u.y); t[2] = f2bs(u.z); t[3] = f2bs(u.w);
            t[4] = f2bs(v.x); t[5] = f2bs(v.y); t[6] = f2bs(v.z); t[7] = f2bs(v.w);
            a[ks] = t;
        }
        f32x4 acc[2] = {{0.f,0.f,0.f,0.f},{0.f,0.f,0.f,0.f}};
        #pragma unroll
        for (int ks = 0; ks < 4; ++ks) {
            #pragma unroll
            for (int nt = 0; nt < 2; ++nt) {
                acc[nt] = __builtin_amdgcn_mfma_f32_16x16x32_bf16(a[ks], bhi[nt][ks], acc[nt], 0, 0, 0);
                acc[nt] = __builtin_amdgcn_mfma_f32_16x16x32_bf16(a[ks], blo[nt][ks], acc[nt], 0, 0, 0);
            }
        }
        float4 xbv = *(const float4*)(xb + nb + q * 4);
        float xbr[4] = {xbv.x, xbv.y, xbv.z, xbv.w};
        #pragma unroll
        for (int nt = 0; nt < 2; ++nt) {
            int ch = wave * 32 + nt * 16 + n;
            bf16* dstp = (ch < 64) ? xl : xr;
            int cc = ch & 63;
            #pragma unroll
            for (int r = 0; r < 4; ++r) {
                int node = nb + q * 4 + r;   // C/D: row = quad*4 + reg
                float val = acc[nt][r] + xbr[r] * w128[nt] + biasv[nt];
                dstp[(size_t)node * H_DIM + cc] = __float2bfloat16(val);
            }
        }
    }
}

// ---------------------------------------------------------------------------
// CSR build: count -> 2-level exclusive scan -> scatter src ids by dst.
// ---------------------------------------------------------------------------
__global__ __launch_bounds__(256) void count_kernel(
    const int* __restrict__ edst, int* __restrict__ cnt)
{
    int e = blockIdx.x * 256 + threadIdx.x;
    if (e < N_EDGES) atomicAdd(&cnt[edst[e]], 1);
}

__global__ __launch_bounds__(256) void scan_a_kernel(
    const int* __restrict__ cnt, int* __restrict__ offs, int* __restrict__ bsum)
{
    __shared__ int s[256];
    int tid = threadIdx.x;
    int i = blockIdx.x * 256 + tid;
    int v = (i < N_NODES) ? cnt[i] : 0;
    s[tid] = v;
    __syncthreads();
    #pragma unroll
    for (int d = 1; d < 256; d <<= 1) {
        int t = (tid >= d) ? s[tid - d] : 0;
        __syncthreads();
        s[tid] += t;
        __syncthreads();
    }
    offs[i] = s[tid] - v;
    if (tid == 255) bsum[blockIdx.x] = s[255];
}

__global__ __launch_bounds__(256) void scan_b_kernel(int* __restrict__ bsum)
{
    __shared__ int s[256];
    int tid = threadIdx.x;
    int v = (tid < 196) ? bsum[tid] : 0;
    s[tid] = v;
    __syncthreads();
    #pragma unroll
    for (int d = 1; d < 256; d <<= 1) {
        int t = (tid >= d) ? s[tid - d] : 0;
        __syncthreads();
        s[tid] += t;
        __syncthreads();
    }
    if (tid < 196) bsum[tid] = s[tid] - v;
}

__global__ __launch_bounds__(256) void scan_c_kernel(
    int* __restrict__ offs, const int* __restrict__ bsum)
{
    int i = blockIdx.x * 256 + threadIdx.x;
    offs[i] += bsum[blockIdx.x];
}

__global__ __launch_bounds__(256) void fill_kernel(
    const int* __restrict__ esrc, const int* __restrict__ edst,
    const int* __restrict__ offs, int* __restrict__ cur,
    int* __restrict__ csr_src)
{
    int e = blockIdx.x * 256 + threadIdx.x;
    if (e >= N_EDGES) return;
    int dst = edst[e];
    int pos = offs[dst] + atomicAdd(&cur[dst], 1);
    csr_src[pos] = esrc[e];
}

// ---------------------------------------------------------------------------
// K2: aggregation, one wave per dst node, no atomics. Value-prefetch: the
// xl[src] gather for edge i+1 is issued before edge i's shfl/exp chain, so
// the ~300cy L2 gather latency overlaps compute. h written bf16 (feeds
// out_mfma's A-frags directly).
// ---------------------------------------------------------------------------
__global__ __launch_bounds__(256) void agg_kernel(
    const int* __restrict__ csr_src, const int* __restrict__ offs,
    const bf16* __restrict__ xl, const bf16* __restrict__ xr,
    const float* __restrict__ att, const float* __restrict__ gb,
    bf16* __restrict__ h)
{
    int wid  = (blockIdx.x * 256 + threadIdx.x) >> 6;   // dst node
    int lane = threadIdx.x & 63;
    if (wid >= N_NODES) return;
    int dst = wid;

    float attv = att[lane];
    float xrv  = b2f(xr[(size_t)dst * H_DIM + lane]);

    // self loop
    float xls = b2f(xl[(size_t)dst * H_DIM + lane]);
    float m = xls + xrv;
    m = (m > 0.f) ? m : 0.2f * m;
    float p = m * attv;
    #pragma unroll
    for (int off = 32; off >= 1; off >>= 1) p += __shfl_xor(p, off);
    float ex  = __expf(p);
    float den = ex;
    float acc = ex * xls;

    int beg = offs[dst], end = offs[dst + 1];
    int i = beg;
    int sB = (i < end) ? csr_src[i] : 0;                // index pipeline (2-deep)
    int sC = (i + 1 < end) ? csr_src[i + 1] : 0;
    float xvA = (i < end) ? b2f(xl[(size_t)sB * H_DIM + lane]) : 0.f;
    sB = sC;
    for (; i < end; ++i) {
        int ip2 = i + 2;
        sC = (ip2 < end) ? csr_src[ip2] : 0;            // prefetch index i+2
        float xvB = (i + 1 < end) ? b2f(xl[(size_t)sB * H_DIM + lane]) : 0.f; // value i+1
        float mm = xvA + xrv;
        mm = (mm > 0.f) ? mm : 0.2f * mm;
        float pp = mm * attv;
        #pragma unroll
        for (int off = 32; off >= 1; off >>= 1) pp += __shfl_xor(pp, off);
        float ee = __expf(pp);
        den += ee;
        acc += ee * xvA;
        xvA = xvB;
        sB = sC;
    }

    float v = acc / den + gb[lane];
    v = (v > 0.f) ? v : expm1f(v);
    h[(size_t)dst * H_DIM + lane] = __float2bfloat16(v);
}

// ---------------------------------------------------------------------------
// K3 (MFMA): logits = h @ Wo^T + bo (+ softplus(dispersion) tail on block 0).
// Same structure as proj_mfma: B-frags (Wo hi/lo) in registers, A-frags are
// b128 loads of the bf16 h rows, K=64 via 2 ksteps.
// ---------------------------------------------------------------------------
__global__ __launch_bounds__(256) void out_mfma(
    const bf16* __restrict__ h,
    const bf16* __restrict__ wohi, const bf16* __restrict__ wolo,
    const float* __restrict__ bo, const float* __restrict__ disp,
    float* __restrict__ out)
{
    if (blockIdx.x == 0 && threadIdx.x < F_DIM) {
        float d = disp[threadIdx.x];
        out[(size_t)N_NODES * F_DIM + threadIdx.x] = (d > 20.f) ? d : log1pf(__expf(d));
    }

    int wave = threadIdx.x >> 6;
    int lane = threadIdx.x & 63;
    int n = lane & 15, q = lane >> 4;
    int node0 = blockIdx.x * 64;

    bf16x8 bhi[2][2], blo[2][2];
    float bov[2];
    #pragma unroll
    for (int nt = 0; nt < 2; ++nt) {
        int ch = wave * 32 + nt * 16 + n;
        #pragma unroll
        for (int ks = 0; ks < 2; ++ks) {
            bhi[nt][ks] = *(const bf16x8*)(wohi + ch * WOS + ks * 32 + q * 8);
            blo[nt][ks] = *(const bf16x8*)(wolo + ch * WOS + ks * 32 + q * 8);
        }
        bov[nt] = bo[ch];
    }

    #pragma unroll
    for (int mt = 0; mt < 4; ++mt) {
        int nb = node0 + mt * 16;
        if (nb >= N_NODES) break;
        const bf16* hrow = h + (size_t)(nb + n) * H_DIM;
        bf16x8 a[2];
        #pragma unroll
        for (int ks = 0; ks < 2; ++ks)
            a[ks] = *(const bf16x8*)(hrow + ks * 32 + q * 8);
        f32x4 acc[2] = {{0.f,0.f,0.f,0.f},{0.f,0.f,0.f,0.f}};
        #pragma unroll
        for (int ks = 0; ks < 2; ++ks) {
            #pragma unroll
            for (int nt = 0; nt < 2; ++nt) {
                acc[nt] = __builtin_amdgcn_mfma_f32_16x16x32_bf16(a[ks], bhi[nt][ks], acc[nt], 0, 0, 0);
                acc[nt] = __builtin_amdgcn_mfma_f32_16x16x32_bf16(a[ks], blo[nt][ks], acc[nt], 0, 0, 0);
            }
        }
        #pragma unroll
        for (int nt = 0; nt < 2; ++nt) {
            int ch = wave * 32 + nt * 16 + n;
            #pragma unroll
            for (int r = 0; r < 4; ++r) {
                int node = nb + q * 4 + r;
                out[(size_t)node * F_DIM + ch] = acc[nt][r] + bov[nt];
            }
        }
    }
}

// ---------------------------------------------------------------------------
extern "C" void kernel_launch(void* const* d_in, const int* in_sizes, int n_in,
                              void* d_out, int out_size, void* d_ws, size_t ws_size,
                              hipStream_t stream)
{
    const float* xf  = (const float*)d_in[0];
    const float* xb  = (const float*)d_in[1];
    const int*   ei  = (const int*)d_in[2];    // [2, E] int32, row-major
    const float* Wl  = (const float*)d_in[3];
    const float* bl  = (const float*)d_in[4];
    const float* Wr  = (const float*)d_in[5];
    const float* br  = (const float*)d_in[6];
    const float* att = (const float*)d_in[7];
    const float* gb  = (const float*)d_in[8];
    const float* Wo  = (const float*)d_in[9];
    const float* bo  = (const float*)d_in[10];
    const float* dp  = (const float*)d_in[11];
    float* out = (float*)d_out;
    const int* esrc = ei;
    const int* edst = ei + N_EDGES;

    // ws layout (16B-aligned segments):
    //  xl bf16[N*64] | xr bf16[N*64] | h bf16[N*64] | csr_src int[E] |
    //  cnt int[NPAD] | cur int[NPAD] | offs int[NPAD] | bsum int[256] |
    //  wphi bf16[128*WPS] | wplo | wohi bf16[128*WOS] | wolo |
    //  wcol f32[128] | biasP f32[128]
    char* ws = (char*)d_ws;
    const size_t SZB = (size_t)N_NODES * H_DIM * sizeof(bf16);   // 6.4 MB
    bf16*  xl      = (bf16*)(ws);
    bf16*  xr      = (bf16*)(ws + SZB);
    bf16*  h       = (bf16*)(ws + 2 * SZB);
    int*   csr_src = (int*)(ws + 3 * SZB);
    int*   cnt     = (int*)(ws + 3 * SZB + (size_t)N_EDGES * 4);
    int*   cur     = cnt + NPAD;
    int*   offs    = cur + NPAD;
    int*   bsum    = offs + NPAD;
    bf16*  wphi    = (bf16*)(bsum + 256);
    bf16*  wplo    = wphi + 128 * WPS;
    bf16*  wohi    = wplo + 128 * WPS;
    bf16*  wolo    = wohi + 128 * WOS;
    float* wcol    = (float*)(wolo + 128 * WOS);
    float* biasP   = wcol + 128;

    hipMemsetAsync(cnt, 0, 2 * NPAD * sizeof(int), stream);

    prep_kernel<<<32, 256, 0, stream>>>(Wl, bl, Wr, br, Wo,
                                        wphi, wplo, wcol, biasP, wohi, wolo);

    proj_mfma<<<(N_NODES + 63) / 64, 256, 0, stream>>>(xf, xb, wphi, wplo,
                                                       wcol, biasP, xl, xr);

    count_kernel<<<N_EDGES / 256, 256, 0, stream>>>(edst, cnt);
    scan_a_kernel<<<NPAD / 256, 256, 0, stream>>>(cnt, offs, bsum);
    scan_b_kernel<<<1, 256, 0, stream>>>(bsum);
    scan_c_kernel<<<NPAD / 256, 256, 0, stream>>>(offs, bsum);
    fill_kernel<<<N_EDGES / 256, 256, 0, stream>>>(esrc, edst, offs, cur, csr_src);

    agg_kernel<<<(N_NODES * 64) / 256, 256, 0, stream>>>(csr_src, offs, xl, xr,
                                                         att, gb, h);

    out_mfma<<<(N_NODES + 63) / 64, 256, 0, stream>>>(h, wohi, wolo, bo, dp, out);
}